// Round 1
// baseline (408.635 us; speedup 1.0000x reference)
//
#include <hip/hip_runtime.h>
#include <hip/hip_bf16.h>

#define BB 4
#define TT 4096
#define NTOK (BB * TT)   // 16384
#define DD 1024
#define HH 64

typedef __attribute__((ext_vector_type(8))) __bf16 bf16x8;
typedef __attribute__((ext_vector_type(8))) unsigned short ushort8;
typedef __attribute__((ext_vector_type(4))) float f32x4;
typedef __attribute__((ext_vector_type(4))) float f4;
typedef unsigned short u16;

__device__ inline u16 f2bf(float f) {
  unsigned u = __builtin_bit_cast(unsigned, f);
  u += 0x7FFFu + ((u >> 16) & 1u);   // RNE
  return (u16)(u >> 16);
}
__device__ inline float bf2f(u16 s) {
  unsigned u = ((unsigned)s) << 16;
  return __builtin_bit_cast(float, u);
}
__device__ inline __bf16 bfbits(u16 s) { return __builtin_bit_cast(__bf16, s); }

__device__ inline f32x4 mfma16(bf16x8 a, bf16x8 b, f32x4 c) {
  return __builtin_amdgcn_mfma_f32_16x16x32_bf16(a, b, c, 0, 0, 0);
}

// ---------------------------------------------------------------------------
// Projection: q/k/v = x @ W^T + b.  M=16384 rows, N=192 (Q|K|V x 64), K=1024.
// Q,K computed in hi/lo bf16 split (3 MFMAs) for score accuracy; V hi only.
// Outputs: qhi,qlo,khi,klo row-major [NTOK][64]; vt transposed [64][NTOK].
// ---------------------------------------------------------------------------
__global__ __launch_bounds__(256) void proj_kernel(
    const float* __restrict__ x,
    const float* __restrict__ Wq, const float* __restrict__ bq,
    const float* __restrict__ Wk, const float* __restrict__ bk,
    const float* __restrict__ Wv, const float* __restrict__ bv,
    u16* __restrict__ qhi, u16* __restrict__ qlo,
    u16* __restrict__ khi, u16* __restrict__ klo,
    u16* __restrict__ vt)
{
  __shared__ __attribute__((aligned(16))) u16 whi[192][40];  // 32 k + pad(8)
  __shared__ __attribute__((aligned(16))) u16 wlo[192][40];
  const int tid = threadIdx.x;
  const int lane = tid & 63;
  const int w = tid >> 6;
  const int l15 = lane & 15;
  const int g4 = lane >> 4;
  const int r0 = blockIdx.x * 64;
  const int mrow = r0 + w * 16 + l15;   // A-fragment row this lane supplies

  f32x4 acc[12];
#pragma unroll
  for (int i = 0; i < 12; ++i) acc[i] = (f32x4){0.f, 0.f, 0.f, 0.f};

  for (int k0 = 0; k0 < DD; k0 += 32) {
    // ---- stage W slab [192 rows][32 k] as hi/lo bf16 into LDS ----
#pragma unroll
    for (int i = 0; i < 3; ++i) {
      const int cc = tid + 256 * i;        // 0..767
      const int n = cc >> 2;               // 0..191
      const int kk = (cc & 3) * 8;
      const float* wrow = (n < 64) ? (Wq + n * DD)
                        : (n < 128) ? (Wk + (n - 64) * DD)
                                    : (Wv + (n - 128) * DD);
      const f4 a = *(const f4*)(wrow + k0 + kk);
      const f4 b = *(const f4*)(wrow + k0 + kk + 4);
      ushort8 h, l;
#pragma unroll
      for (int j = 0; j < 8; ++j) {
        const float f = (j < 4) ? a[j] : b[j - 4];
        const u16 hh = f2bf(f);
        h[j] = hh;
        l[j] = f2bf(f - bf2f(hh));
      }
      *(ushort8*)&whi[n][kk] = h;
      *(ushort8*)&wlo[n][kk] = l;
    }
    __syncthreads();
    // ---- x fragment hi/lo (A operand): row=l15, k-chunk=g4 ----
    const float* xs = x + (size_t)mrow * DD + k0 + g4 * 8;
    const f4 xa = *(const f4*)xs;
    const f4 xb = *(const f4*)(xs + 4);
    bf16x8 xhi, xlo;
#pragma unroll
    for (int j = 0; j < 8; ++j) {
      const float f = (j < 4) ? xa[j] : xb[j - 4];
      const u16 hh = f2bf(f);
      xhi[j] = bfbits(hh);
      xlo[j] = bfbits(f2bf(f - bf2f(hh)));
    }
    // ---- MFMA over 12 N-tiles ----
#pragma unroll
    for (int nt = 0; nt < 12; ++nt) {
      const int n = nt * 16 + l15;
      const bf16x8 bhi = *(const bf16x8*)&whi[n][g4 * 8];
      acc[nt] = mfma16(xhi, bhi, acc[nt]);
      if (nt < 8) {  // Q,K need the hi/lo cross terms
        const bf16x8 blo = *(const bf16x8*)&wlo[n][g4 * 8];
        acc[nt] = mfma16(xhi, blo, acc[nt]);
        acc[nt] = mfma16(xlo, bhi, acc[nt]);
      }
    }
    __syncthreads();
  }
  // ---- epilogue: bias add + hi/lo store ----
  const int orow0 = r0 + w * 16 + g4 * 4;  // D row = 4*(lane>>4)+rr
#pragma unroll
  for (int nt = 0; nt < 12; ++nt) {
    const int hcol = (nt & 3) * 16 + l15;  // D col = lane&15
    const float* bias = (nt < 4) ? bq : (nt < 8) ? bk : bv;
    const float bb = bias[hcol];
#pragma unroll
    for (int rr = 0; rr < 4; ++rr) {
      const int gg = orow0 + rr;
      const float val = acc[nt][rr] + bb;
      const u16 hh = f2bf(val);
      if (nt < 4) {
        qhi[(size_t)gg * HH + hcol] = hh;
        qlo[(size_t)gg * HH + hcol] = f2bf(val - bf2f(hh));
      } else if (nt < 8) {
        khi[(size_t)gg * HH + hcol] = hh;
        klo[(size_t)gg * HH + hcol] = f2bf(val - bf2f(hh));
      } else {
        vt[(size_t)hcol * NTOK + gg] = hh;
      }
    }
  }
}

// ---------------------------------------------------------------------------
// Flash attention, roles swapped: roleQ = k-proj, roleK = q-proj, V = v.
// out[i] = sum_{j<=i} softmax_j(k_i . q_j) v_j.  No scale.
// Each wave owns a 16-row tile; waves of a block take complementary tiles
// {2g, 2g+1, 254-2g, 255-2g} for perfect causal load balance. No barriers.
// ---------------------------------------------------------------------------
__global__ __launch_bounds__(256) void attn_kernel(
    const u16* __restrict__ qhi, const u16* __restrict__ qlo,
    const u16* __restrict__ khi, const u16* __restrict__ klo,
    const u16* __restrict__ vt, float* __restrict__ out)
{
  __shared__ __attribute__((aligned(16))) u16 plds[4][16][72];  // wave-private P
  const int tid = threadIdx.x;
  const int lane = tid & 63;
  const int w = tid >> 6;
  const int l15 = lane & 15;
  const int g4 = lane >> 4;
  const int b = blockIdx.x >> 6;   // batch
  const int g = blockIdx.x & 63;
  const int tw = (w == 0) ? 2 * g : (w == 1) ? 2 * g + 1
               : (w == 2) ? 254 - 2 * g : 255 - 2 * g;   // 16-row tile index
  const int rowbase = tw * 16;

  // hoisted roleQ (= k-proj) A-fragments, hi and lo, 2 k-steps over headdim 64
  bf16x8 kh[2], kl2[2];
  {
    const size_t koff = (size_t)(b * TT + rowbase + l15) * HH + g4 * 8;
    kh[0] = *(const bf16x8*)(khi + koff);
    kh[1] = *(const bf16x8*)(khi + koff + 32);
    kl2[0] = *(const bf16x8*)(klo + koff);
    kl2[1] = *(const bf16x8*)(klo + koff + 32);
  }

  float m[4], lsum[4];
  f32x4 O[4];
#pragma unroll
  for (int rr = 0; rr < 4; ++rr) { m[rr] = -INFINITY; lsum[rr] = 0.f; }
#pragma unroll
  for (int ht = 0; ht < 4; ++ht) O[ht] = (f32x4){0.f, 0.f, 0.f, 0.f};

  const int njt = tw / 4 + 1;   // causal col-tile count (BC=64)
  for (int jt = 0; jt < njt; ++jt) {
    const int j0 = jt * 64;
    f32x4 S[4];
#pragma unroll
    for (int nt = 0; nt < 4; ++nt) S[nt] = (f32x4){0.f, 0.f, 0.f, 0.f};
#pragma unroll
    for (int nt = 0; nt < 4; ++nt) {
      const size_t qoff = (size_t)(b * TT + j0 + nt * 16 + l15) * HH + g4 * 8;
      const bf16x8 q0 = *(const bf16x8*)(qhi + qoff);
      const bf16x8 q1 = *(const bf16x8*)(qhi + qoff + 32);
      const bf16x8 ql0 = *(const bf16x8*)(qlo + qoff);
      const bf16x8 ql1 = *(const bf16x8*)(qlo + qoff + 32);
      S[nt] = mfma16(kh[0], q0, S[nt]);
      S[nt] = mfma16(kh[1], q1, S[nt]);
      S[nt] = mfma16(kh[0], ql0, S[nt]);
      S[nt] = mfma16(kh[1], ql1, S[nt]);
      S[nt] = mfma16(kl2[0], q0, S[nt]);
      S[nt] = mfma16(kl2[1], q1, S[nt]);
    }
    if (jt == njt - 1) {  // diagonal tile: mask j > i
#pragma unroll
      for (int nt = 0; nt < 4; ++nt)
#pragma unroll
        for (int rr = 0; rr < 4; ++rr) {
          const int jj = j0 + nt * 16 + l15;
          const int ii = rowbase + g4 * 4 + rr;
          if (jj > ii) S[nt][rr] = -INFINITY;
        }
    }
    // online softmax: row stats across the 16-lane col group
    float mnew[4], sc[4];
#pragma unroll
    for (int rr = 0; rr < 4; ++rr) {
      float tm = fmaxf(fmaxf(S[0][rr], S[1][rr]), fmaxf(S[2][rr], S[3][rr]));
      tm = fmaxf(tm, __shfl_xor(tm, 1));
      tm = fmaxf(tm, __shfl_xor(tm, 2));
      tm = fmaxf(tm, __shfl_xor(tm, 4));
      tm = fmaxf(tm, __shfl_xor(tm, 8));
      mnew[rr] = fmaxf(m[rr], tm);
      sc[rr] = __expf(m[rr] - mnew[rr]);
      m[rr] = mnew[rr];
    }
    float p[4][4];
#pragma unroll
    for (int nt = 0; nt < 4; ++nt)
#pragma unroll
      for (int rr = 0; rr < 4; ++rr)
        p[nt][rr] = __expf(S[nt][rr] - mnew[rr]);
#pragma unroll
    for (int rr = 0; rr < 4; ++rr) {
      float s = p[0][rr] + p[1][rr] + p[2][rr] + p[3][rr];
      s += __shfl_xor(s, 1);
      s += __shfl_xor(s, 2);
      s += __shfl_xor(s, 4);
      s += __shfl_xor(s, 8);
      lsum[rr] = lsum[rr] * sc[rr] + s;
#pragma unroll
      for (int ht = 0; ht < 4; ++ht) O[ht][rr] *= sc[rr];
    }
    // P -> LDS (bf16), D-layout write, A-layout read (wave-private, no barrier)
#pragma unroll
    for (int nt = 0; nt < 4; ++nt)
#pragma unroll
      for (int rr = 0; rr < 4; ++rr)
        plds[w][g4 * 4 + rr][nt * 16 + l15] = f2bf(p[nt][rr]);
    const bf16x8 pf0 = *(const bf16x8*)&plds[w][l15][g4 * 8];
    const bf16x8 pf1 = *(const bf16x8*)&plds[w][l15][32 + g4 * 8];
    // PV: B operand from v^T (contiguous in j)
#pragma unroll
    for (int ht = 0; ht < 4; ++ht) {
      const u16* vp = vt + (size_t)(ht * 16 + l15) * NTOK + b * TT + j0 + g4 * 8;
      const bf16x8 v0 = *(const bf16x8*)vp;
      const bf16x8 v1 = *(const bf16x8*)(vp + 32);
      O[ht] = mfma16(pf0, v0, O[ht]);
      O[ht] = mfma16(pf1, v1, O[ht]);
    }
  }
  // epilogue: normalize + store fp32
#pragma unroll
  for (int ht = 0; ht < 4; ++ht)
#pragma unroll
    for (int rr = 0; rr < 4; ++rr) {
      const int ii = rowbase + g4 * 4 + rr;
      out[(size_t)(b * TT + ii) * HH + ht * 16 + l15] = O[ht][rr] / lsum[rr];
    }
}

extern "C" void kernel_launch(void* const* d_in, const int* in_sizes, int n_in,
                              void* d_out, int out_size, void* d_ws, size_t ws_size,
                              hipStream_t stream) {
  (void)in_sizes; (void)n_in; (void)out_size; (void)ws_size;
  const float* x  = (const float*)d_in[0];
  const float* Wq = (const float*)d_in[1];
  const float* bq = (const float*)d_in[2];
  const float* Wk = (const float*)d_in[3];
  const float* bk = (const float*)d_in[4];
  const float* Wv = (const float*)d_in[5];
  const float* bv = (const float*)d_in[6];
  float* out = (float*)d_out;

  u16* ws  = (u16*)d_ws;
  u16* qhi = ws;                    // [NTOK][64]
  u16* qlo = qhi + (size_t)NTOK * HH;
  u16* khi = qlo + (size_t)NTOK * HH;
  u16* klo = khi + (size_t)NTOK * HH;
  u16* vt  = klo + (size_t)NTOK * HH;  // [64][NTOK]

  proj_kernel<<<256, 256, 0, stream>>>(x, Wq, bq, Wk, bk, Wv, bv,
                                       qhi, qlo, khi, klo, vt);
  attn_kernel<<<256, 256, 0, stream>>>(qhi, qlo, khi, klo, vt, out);
}

// Round 2
// 282.732 us; speedup vs baseline: 1.4453x; 1.4453x over previous
//
#include <hip/hip_runtime.h>
#include <hip/hip_bf16.h>

#define BB 4
#define TT 4096
#define NTOK (BB * TT)   // 16384
#define DD 1024
#define HH 64

typedef __attribute__((ext_vector_type(8))) __bf16 bf16x8;
typedef __attribute__((ext_vector_type(8))) unsigned short ushort8;
typedef __attribute__((ext_vector_type(4))) float f32x4;
typedef __attribute__((ext_vector_type(4))) float f4;
typedef unsigned short u16;
typedef unsigned int u32;

__device__ __forceinline__ u16 f2bf(float f) {
  unsigned u = __builtin_bit_cast(unsigned, f);
  u += 0x7FFFu + ((u >> 16) & 1u);   // RNE
  return (u16)(u >> 16);
}
__device__ __forceinline__ float bf2f(u16 s) {
  unsigned u = ((unsigned)s) << 16;
  return __builtin_bit_cast(float, u);
}
__device__ __forceinline__ __bf16 bfbits(u16 s) { return __builtin_bit_cast(__bf16, s); }

__device__ __forceinline__ f32x4 mfma16(bf16x8 a, bf16x8 b, f32x4 c) {
  return __builtin_amdgcn_mfma_f32_16x16x32_bf16(a, b, c, 0, 0, 0);
}

__device__ __forceinline__ void gl_lds16(const u16* g, u16* l) {
  __builtin_amdgcn_global_load_lds(
      (const __attribute__((address_space(1))) u32*)(const void*)g,
      (__attribute__((address_space(3))) u32*)(void*)l, 16, 0, 0);
}

// ---------------------------------------------------------------------------
// prep_w: convert W (fp32) -> bf16 hi/lo, pre-tiled [16 kt][64 n][64 kk] with
// chunk swizzle (16B chunk j stored at j^(n&7)) so proj can stage via
// global_load_lds (linear) and ds_read conflict-free.
// Arrays: 0=Wq_hi 1=Wq_lo 2=Wk_hi 3=Wk_lo 4=Wv_hi, each 65536 u16.
// ---------------------------------------------------------------------------
__global__ __launch_bounds__(256) void prep_w(
    const float* __restrict__ Wq, const float* __restrict__ Wk,
    const float* __restrict__ Wv, u16* __restrict__ wpre)
{
  const int c = blockIdx.x * 256 + threadIdx.x;   // 40960 chunks
  const int arr = c >> 13;          // 8192 chunks per array
  const int rem = c & 8191;
  const int kt = rem >> 9;          // 512 chunks per k-tile
  const int n  = (rem >> 3) & 63;
  const int j  = rem & 7;
  const float* W = (arr <= 1) ? Wq : (arr <= 3) ? Wk : Wv;
  const bool lo = (arr == 1) || (arr == 3);
  const float* src = W + (size_t)n * DD + kt * 64 + j * 8;
  ushort8 out;
#pragma unroll
  for (int e = 0; e < 8; ++e) {
    const float f = src[e];
    const u16 h = f2bf(f);
    out[e] = lo ? f2bf(f - bf2f(h)) : h;
  }
  u16* dst = wpre + (size_t)arr * 65536 + kt * 4096 + n * 64 + (j ^ (n & 7)) * 8;
  *(ushort8*)dst = out;
}

// ---------------------------------------------------------------------------
// Projection: blockIdx.x = rowblock(256) + 256*type (0=Q,1=K,2=V).
// 64 rows x 64 cols per block, BK=64, double-buffered global_load_lds staging.
// Q,K: hi/lo 3-MFMA; V: hi only. Outputs qhi/qlo/khi/klo [NTOK][64], vt [64][NTOK].
// ---------------------------------------------------------------------------
__global__ __launch_bounds__(256) void proj_kernel(
    const float* __restrict__ x,
    const float* __restrict__ bq, const float* __restrict__ bk,
    const float* __restrict__ bv, const u16* __restrict__ wpre,
    u16* __restrict__ qhi, u16* __restrict__ qlo,
    u16* __restrict__ khi, u16* __restrict__ klo,
    u16* __restrict__ vt)
{
  __shared__ __attribute__((aligned(16))) u16 lhi[2][4096];
  __shared__ __attribute__((aligned(16))) u16 llo[2][4096];
  const int tid = threadIdx.x;
  const int w = tid >> 6;
  const int lane = tid & 63;
  const int l15 = lane & 15;
  const int g4 = lane >> 4;
  const int rb = blockIdx.x & 255;
  const int type = blockIdx.x >> 8;
  const bool isv = (type == 2);
  const u16* srchi = wpre + (size_t)((type == 0) ? 0 : (type == 1) ? 2 : 4) * 65536;
  const u16* srclo = srchi + 65536;
  const int mrow = rb * 64 + w * 16 + l15;
  const float* xrow = x + (size_t)mrow * DD;

  f32x4 acc[4];
#pragma unroll
  for (int i = 0; i < 4; ++i) acc[i] = (f32x4){0.f, 0.f, 0.f, 0.f};

  // stage kt into buffer buf
  auto stage = [&](int buf, int kt) {
    const size_t base = (size_t)kt * 4096;
#pragma unroll
    for (int i = 0; i < 2; ++i) {
      const int chunk = i * 256 + tid;
      gl_lds16(srchi + base + chunk * 8, &lhi[buf][(i * 256 + w * 64) * 8]);
      if (!isv)
        gl_lds16(srclo + base + chunk * 8, &llo[buf][(i * 256 + w * 64) * 8]);
    }
  };

  stage(0, 0);
  __syncthreads();
  int cur = 0;
  for (int kt = 0; kt < 16; ++kt) {
    if (kt < 15) stage(cur ^ 1, kt + 1);
    // x A-fragments (hi/lo), 2 k-subtiles
    bf16x8 xh[2], xl[2];
#pragma unroll
    for (int ksub = 0; ksub < 2; ++ksub) {
      const float* xs = xrow + kt * 64 + ksub * 32 + g4 * 8;
      const f4 a = *(const f4*)xs;
      const f4 bv4 = *(const f4*)(xs + 4);
#pragma unroll
      for (int j = 0; j < 8; ++j) {
        const float f = (j < 4) ? a[j] : bv4[j - 4];
        const u16 h = f2bf(f);
        xh[ksub][j] = bfbits(h);
        xl[ksub][j] = bfbits(f2bf(f - bf2f(h)));
      }
    }
    // MFMA over 4 N-tiles x 2 ksub, swizzled ds_read
#pragma unroll
    for (int ksub = 0; ksub < 2; ++ksub)
#pragma unroll
      for (int nt = 0; nt < 4; ++nt) {
        const int eoff = (nt * 16 + l15) * 64 + (((ksub * 4 + g4) ^ (l15 & 7)) * 8);
        const bf16x8 bhi = *(const bf16x8*)&lhi[cur][eoff];
        acc[nt] = mfma16(xh[ksub], bhi, acc[nt]);
        if (!isv) {
          const bf16x8 blo = *(const bf16x8*)&llo[cur][eoff];
          acc[nt] = mfma16(xh[ksub], blo, acc[nt]);
          acc[nt] = mfma16(xl[ksub], bhi, acc[nt]);
        }
      }
    __syncthreads();
    cur ^= 1;
  }
  // epilogue
  const float* bias = (type == 0) ? bq : (type == 1) ? bk : bv;
#pragma unroll
  for (int nt = 0; nt < 4; ++nt) {
    const int col = nt * 16 + l15;
    const float bb = bias[col];
#pragma unroll
    for (int rr = 0; rr < 4; ++rr) {
      const int row = rb * 64 + w * 16 + g4 * 4 + rr;
      const float val = acc[nt][rr] + bb;
      const u16 h = f2bf(val);
      if (type == 0) {
        qhi[(size_t)row * HH + col] = h;
        qlo[(size_t)row * HH + col] = f2bf(val - bf2f(h));
      } else if (type == 1) {
        khi[(size_t)row * HH + col] = h;
        klo[(size_t)row * HH + col] = f2bf(val - bf2f(h));
      } else {
        vt[(size_t)col * NTOK + row] = h;
      }
    }
  }
}

// ---------------------------------------------------------------------------
// Flash attention (roles swapped), split along j for occupancy.
// Task = (batch, 16-row tile tw, split s); split covers j-tiles [8s, min(8s+8,njt)).
// Group g = tw>>5 has nsplit = g+1 (njt = tw/4+1 in [8g+1, 8g+8]).
// Each wave = one task; writes raw partials (m, l, O) to ws.
// ---------------------------------------------------------------------------
__global__ __launch_bounds__(256) void attn_kernel(
    const u16* __restrict__ qhi, const u16* __restrict__ qlo,
    const u16* __restrict__ khi, const u16* __restrict__ klo,
    const u16* __restrict__ vt, float* __restrict__ Opart,
    float* __restrict__ ml)
{
  __shared__ __attribute__((aligned(16))) u16 plds[4][16][72];
  const int tid = threadIdx.x;
  const int lane = tid & 63;
  const int w = tid >> 6;
  const int l15 = lane & 15;
  const int g4 = lane >> 4;

  const int task = blockIdx.x * 4 + w;     // < 4608
  const int b = task / 1152;
  const int t = task - b * 1152;
  int g = 0;
#pragma unroll
  for (int gg = 1; gg < 8; ++gg)
    if (t >= 16 * gg * (gg + 1)) g = gg;
  const int r = t - 16 * g * (g + 1);
  const int den = g + 1;
  const int tile = r / den;
  const int s = r - tile * den;
  const int tw = g * 32 + tile;
  const int rowbase = tw * 16;
  const int njt = (tw >> 2) + 1;
  const int jt0 = s * 8;
  const int jtend = (jt0 + 8 < njt) ? jt0 + 8 : njt;

  // hoisted roleQ (= k-proj) fragments
  bf16x8 kh[2], kl2[2];
  {
    const size_t koff = (size_t)(b * TT + rowbase + l15) * HH + g4 * 8;
    kh[0] = *(const bf16x8*)(khi + koff);
    kh[1] = *(const bf16x8*)(khi + koff + 32);
    kl2[0] = *(const bf16x8*)(klo + koff);
    kl2[1] = *(const bf16x8*)(klo + koff + 32);
  }

  float m[4], lsum[4];
  f32x4 O[4];
#pragma unroll
  for (int rr = 0; rr < 4; ++rr) { m[rr] = -INFINITY; lsum[rr] = 0.f; }
#pragma unroll
  for (int ht = 0; ht < 4; ++ht) O[ht] = (f32x4){0.f, 0.f, 0.f, 0.f};

  for (int jt = jt0; jt < jtend; ++jt) {
    const int j0 = jt * 64;
    f32x4 S[4];
#pragma unroll
    for (int nt = 0; nt < 4; ++nt) S[nt] = (f32x4){0.f, 0.f, 0.f, 0.f};
#pragma unroll
    for (int nt = 0; nt < 4; ++nt) {
      const size_t qoff = (size_t)(b * TT + j0 + nt * 16 + l15) * HH + g4 * 8;
      const bf16x8 q0 = *(const bf16x8*)(qhi + qoff);
      const bf16x8 q1 = *(const bf16x8*)(qhi + qoff + 32);
      const bf16x8 ql0 = *(const bf16x8*)(qlo + qoff);
      const bf16x8 ql1 = *(const bf16x8*)(qlo + qoff + 32);
      S[nt] = mfma16(kh[0], q0, S[nt]);
      S[nt] = mfma16(kh[1], q1, S[nt]);
      S[nt] = mfma16(kh[0], ql0, S[nt]);
      S[nt] = mfma16(kh[1], ql1, S[nt]);
      S[nt] = mfma16(kl2[0], q0, S[nt]);
      S[nt] = mfma16(kl2[1], q1, S[nt]);
    }
    if (jt == njt - 1) {  // diagonal tile: mask j > i
#pragma unroll
      for (int nt = 0; nt < 4; ++nt)
#pragma unroll
        for (int rr = 0; rr < 4; ++rr) {
          const int jj = j0 + nt * 16 + l15;
          const int ii = rowbase + g4 * 4 + rr;
          if (jj > ii) S[nt][rr] = -INFINITY;
        }
    }
    // online softmax across the 16-lane col group
    float mnew[4], sc[4];
#pragma unroll
    for (int rr = 0; rr < 4; ++rr) {
      float tm = fmaxf(fmaxf(S[0][rr], S[1][rr]), fmaxf(S[2][rr], S[3][rr]));
      tm = fmaxf(tm, __shfl_xor(tm, 1));
      tm = fmaxf(tm, __shfl_xor(tm, 2));
      tm = fmaxf(tm, __shfl_xor(tm, 4));
      tm = fmaxf(tm, __shfl_xor(tm, 8));
      mnew[rr] = fmaxf(m[rr], tm);
      sc[rr] = __expf(m[rr] - mnew[rr]);
      m[rr] = mnew[rr];
    }
    float p[4][4];
#pragma unroll
    for (int nt = 0; nt < 4; ++nt)
#pragma unroll
      for (int rr = 0; rr < 4; ++rr)
        p[nt][rr] = __expf(S[nt][rr] - mnew[rr]);
#pragma unroll
    for (int rr = 0; rr < 4; ++rr) {
      float ss = p[0][rr] + p[1][rr] + p[2][rr] + p[3][rr];
      ss += __shfl_xor(ss, 1);
      ss += __shfl_xor(ss, 2);
      ss += __shfl_xor(ss, 4);
      ss += __shfl_xor(ss, 8);
      lsum[rr] = lsum[rr] * sc[rr] + ss;
#pragma unroll
      for (int ht = 0; ht < 4; ++ht) O[ht][rr] *= sc[rr];
    }
    // P -> LDS (bf16), D-layout write, A-layout read (wave-private)
#pragma unroll
    for (int nt = 0; nt < 4; ++nt)
#pragma unroll
      for (int rr = 0; rr < 4; ++rr)
        plds[w][g4 * 4 + rr][nt * 16 + l15] = f2bf(p[nt][rr]);
    const bf16x8 pf0 = *(const bf16x8*)&plds[w][l15][g4 * 8];
    const bf16x8 pf1 = *(const bf16x8*)&plds[w][l15][32 + g4 * 8];
#pragma unroll
    for (int ht = 0; ht < 4; ++ht) {
      const u16* vp = vt + (size_t)(ht * 16 + l15) * NTOK + b * TT + j0 + g4 * 8;
      const bf16x8 v0 = *(const bf16x8*)vp;
      const bf16x8 v1 = *(const bf16x8*)(vp + 32);
      O[ht] = mfma16(pf0, v0, O[ht]);
      O[ht] = mfma16(pf1, v1, O[ht]);
    }
  }
  // epilogue: raw partials (no normalization)
  const size_t pb = (size_t)((s * 4 + b) * 256 + tw);
#pragma unroll
  for (int ht = 0; ht < 4; ++ht)
#pragma unroll
    for (int rr = 0; rr < 4; ++rr)
      Opart[pb * 1024 + (g4 * 4 + rr) * 64 + ht * 16 + l15] = O[ht][rr];
  if (l15 == 0) {
#pragma unroll
    for (int rr = 0; rr < 4; ++rr) {
      ml[pb * 16 + g4 * 4 + rr] = m[rr];
      ml[131072 + pb * 16 + g4 * 4 + rr] = lsum[rr];
    }
  }
}

// ---------------------------------------------------------------------------
// Combine: merge up to (tw>>5)+1 split partials per row, normalize, store fp32.
// ---------------------------------------------------------------------------
__global__ __launch_bounds__(256) void combine_kernel(
    const float* __restrict__ Opart, const float* __restrict__ ml,
    float* __restrict__ out)
{
  const int idx = blockIdx.x * 256 + threadIdx.x;  // < 1048576
  const int h = idx & 63;
  const int rg = idx >> 6;          // 0..16383
  const int b = rg >> 12;
  const int i = rg & 4095;
  const int tw = i >> 4;
  const int ro = i & 15;
  const int ns = (tw >> 5) + 1;
  const float* mb = ml;
  const float* lb = ml + 131072;
  float M = -INFINITY;
  for (int s = 0; s < ns; ++s)
    M = fmaxf(M, mb[((s * 4 + b) * 256 + tw) * 16 + ro]);
  float L = 0.f, acc = 0.f;
  for (int s = 0; s < ns; ++s) {
    const int base = ((s * 4 + b) * 256 + tw) * 16 + ro;
    const float e = __expf(mb[base] - M);
    L += e * lb[base];
    acc += e * Opart[(size_t)((s * 4 + b) * 256 + tw) * 1024 + ro * 64 + h];
  }
  out[(size_t)rg * 64 + h] = acc / L;
}

extern "C" void kernel_launch(void* const* d_in, const int* in_sizes, int n_in,
                              void* d_out, int out_size, void* d_ws, size_t ws_size,
                              hipStream_t stream) {
  (void)in_sizes; (void)n_in; (void)out_size; (void)ws_size;
  const float* x  = (const float*)d_in[0];
  const float* Wq = (const float*)d_in[1];
  const float* bq = (const float*)d_in[2];
  const float* Wk = (const float*)d_in[3];
  const float* bk = (const float*)d_in[4];
  const float* Wv = (const float*)d_in[5];
  const float* bv = (const float*)d_in[6];
  float* out = (float*)d_out;

  u16* ws   = (u16*)d_ws;
  u16* wpre = ws;                        // 5*65536 u16
  u16* qhi  = ws + 5 * 65536;
  u16* qlo  = qhi + (size_t)NTOK * HH;
  u16* khi  = qlo + (size_t)NTOK * HH;
  u16* klo  = khi + (size_t)NTOK * HH;
  u16* vt   = klo + (size_t)NTOK * HH;   // [64][NTOK]
  float* Opart = (float*)(vt + (size_t)NTOK * HH);  // 8*4*256*16*64 f32
  float* ml    = Opart + (size_t)8 * 4 * 256 * 16 * 64;  // 2*131072 f32

  prep_w<<<160, 256, 0, stream>>>(Wq, Wk, Wv, wpre);
  proj_kernel<<<768, 256, 0, stream>>>(x, bq, bk, bv, wpre,
                                       qhi, qlo, khi, klo, vt);
  attn_kernel<<<1152, 256, 0, stream>>>(qhi, qlo, khi, klo, vt, Opart, ml);
  combine_kernel<<<4096, 256, 0, stream>>>(Opart, ml, out);
}